// Round 12
// baseline (3696.138 us; speedup 1.0000x reference)
//
#include <hip/hip_runtime.h>
#include <hip/hip_bf16.h>
#include <cmath>

#define B_   32
#define S_   512
#define SP1  513
#define D_   768
#define H_   8
#define HD_  96
#define L_   6
#define DFF_ 3072
#define NTOK (B_*SP1)   // 16416
#define VTP  520        // VtG padded k-stride

typedef short short8 __attribute__((ext_vector_type(8)));
typedef float f32x4  __attribute__((ext_vector_type(4)));

__device__ __forceinline__ short f2bf(float f){
  unsigned u = __float_as_uint(f);
  u += 0x7fffu + ((u >> 16) & 1u);   // RNE
  return (short)(u >> 16);
}

// bijective XCD-aware swizzle (m204)
__device__ __forceinline__ int xcd_swz(int orig, int nwg){
  int q = nwg >> 3, r = nwg & 7;
  int x = orig & 7, idx = orig >> 3;
  return (x < r ? x*(q+1) : r*(q+1) + (x-r)*q) + idx;
}

__device__ __forceinline__ void gload_lds16(const short* g, short* l){
  __builtin_amdgcn_global_load_lds((const __attribute__((address_space(1))) void*)g,
                                   (__attribute__((address_space(3))) void*)l, 16, 0, 0);
}

__device__ __forceinline__ float block_sum256(float v, float* tmp){
  #pragma unroll
  for (int o = 32; o; o >>= 1) v += __shfl_xor(v, o, 64);
  int t = threadIdx.x;
  if ((t & 63) == 0) tmp[t >> 6] = v;
  __syncthreads();
  float r = tmp[0] + tmp[1] + tmp[2] + tmp[3];
  __syncthreads();
  return r;
}

// paired reduction: one barrier pass for (sum, sumsq)
__device__ __forceinline__ void block_sum2(float& a, float& b, float* tmp){
  #pragma unroll
  for (int o = 32; o; o >>= 1){ a += __shfl_xor(a, o, 64); b += __shfl_xor(b, o, 64); }
  int t = threadIdx.x;
  if ((t & 63) == 0){ tmp[(t >> 6)*2] = a; tmp[(t >> 6)*2 + 1] = b; }
  __syncthreads();
  a = tmp[0] + tmp[2] + tmp[4] + tmp[6];
  b = tmp[1] + tmp[3] + tmp[5] + tmp[7];
  __syncthreads();
}

// ---------------- embedding -----------------------------------------------------
__global__ __launch_bounds__(256) void embed_kernel(
    const int* __restrict__ sensor_ids, const int* __restrict__ state_ids,
    const int* __restrict__ room_ids, const float* __restrict__ coords,
    const float* __restrict__ tdelt,
    const float* __restrict__ emb_sensor, const float* __restrict__ emb_state,
    const float* __restrict__ emb_room, const float* __restrict__ fourier_W,
    const float* __restrict__ fourier_b, const float* __restrict__ time_emb,
    const float* __restrict__ cls_tok, const float* __restrict__ pos_emb,
    float* __restrict__ x){
  __shared__ float ffs[16][48];
  __shared__ int meta[16][4];
  int t = threadIdx.x;
  int tok0 = blockIdx.x * 16;
  if (t < 16){
    int tk = tok0 + t;
    int b = tk / SP1, p = tk % SP1;
    int sid=0, stid=0, rid=0, tidx=0;
    if (p){
      int s = p - 1;
      sid  = sensor_ids[b*S_+s]; stid = state_ids[b*S_+s]; rid = room_ids[b*S_+s];
      float td = fmaxf(tdelt[b*S_+s], 1e-6f);
      float fi = logf(td + 1.0f) / logf(3601.0f) * 99.0f;
      int ix = (int)fi;
      tidx = ix < 0 ? 0 : (ix > 99 ? 99 : ix);
    }
    meta[t][0]=sid; meta[t][1]=stid; meta[t][2]=rid; meta[t][3]=tidx;
  }
  for (int i = t; i < 16*24; i += 256){
    int tl = i / 24, r = i % 24;
    int c = r / 12, f = r % 12;
    int tk = tok0 + tl;
    int b = tk / SP1, p = tk % SP1;
    float sv = 0.f, cv = 0.f;
    if (p){
      float ang = coords[((size_t)b*S_ + (p-1))*2 + c] * exp2f((float)f) * 3.14159265358979323846f;
      sv = sinf(ang); cv = cosf(ang);
    }
    ffs[tl][c*24 + f]      = sv;
    ffs[tl][c*24 + 12 + f] = cv;
  }
  __syncthreads();
  for (int dc = 0; dc < 3; dc++){
    int d = dc*256 + t;
    float acc[16];
    #pragma unroll
    for (int tl=0; tl<16; tl++) acc[tl] = 0.f;
    for (int f = 0; f < 48; f++){
      float wv = fourier_W[f*D_ + d];
      #pragma unroll
      for (int tl=0; tl<16; tl++) acc[tl] += ffs[tl][f] * wv;
    }
    float fb = fourier_b[d];
    for (int tl = 0; tl < 16; tl++){
      int tk = tok0 + tl;
      int b = tk / SP1, p = tk % SP1;
      float v;
      if (p == 0) v = cls_tok[d] + pos_emb[d];
      else v = emb_sensor[(size_t)meta[tl][0]*D_ + d] + emb_state[(size_t)meta[tl][1]*D_ + d]
             + emb_room[(size_t)meta[tl][2]*D_ + d] + time_emb[(size_t)meta[tl][3]*D_ + d]
             + fb + acc[tl] + pos_emb[(size_t)p*D_ + d];
      x[(size_t)tk*D_ + d] = v;
    }
  }
}

// ---------------- layernorm (one-pass mean/var) ---------------------------------
template<typename OUT>
__global__ __launch_bounds__(256) void ln_kernel(const float* __restrict__ x,
    const float* __restrict__ g, const float* __restrict__ bb, OUT* __restrict__ out){
  __shared__ float tmp[8];
  int row = blockIdx.x, t = threadIdx.x;
  const float* xr = x + (size_t)row*D_;
  float v0 = xr[t], v1 = xr[t+256], v2 = xr[t+512];
  float s1 = v0+v1+v2, s2 = v0*v0 + v1*v1 + v2*v2;
  block_sum2(s1, s2, tmp);
  float mean = s1 * (1.f/768.f);
  float var  = fmaxf(s2 * (1.f/768.f) - mean*mean, 0.f);
  float rstd = rsqrtf(var + 1e-5f);
  OUT* orow = out + (size_t)row*D_;
  float r0 = (v0-mean)*rstd*g[t]     + bb[t];
  float r1 = (v1-mean)*rstd*g[t+256] + bb[t+256];
  float r2 = (v2-mean)*rstd*g[t+512] + bb[t+512];
  if constexpr (sizeof(OUT) == 2){
    orow[t] = f2bf(r0); orow[t+256] = f2bf(r1); orow[t+512] = f2bf(r2);
  } else {
    orow[t] = r0; orow[t+256] = r1; orow[t+512] = r2;
  }
}

// ---------------- fused 6-weight transpose + f32->bf16 --------------------------
__global__ __launch_bounds__(256) void transpose6_kernel(
    const float* __restrict__ Wq, const float* __restrict__ Wk,
    const float* __restrict__ Wv, const float* __restrict__ Wo,
    const float* __restrict__ W1, const float* __restrict__ W2,
    short* __restrict__ wqkvT, short* __restrict__ woT,
    short* __restrict__ w1T, short* __restrict__ w2T){
  __shared__ float tile[32][33];
  int bid = blockIdx.x;
  const float* W; short* WT; int K, Nn, tb;
  if (bid < 576)       { W=Wq; WT=wqkvT;                    K=768;  Nn=768;  tb=bid; }
  else if (bid < 1152) { W=Wk; WT=wqkvT+(size_t)768*768;    K=768;  Nn=768;  tb=bid-576; }
  else if (bid < 1728) { W=Wv; WT=wqkvT+(size_t)1536*768;   K=768;  Nn=768;  tb=bid-1152; }
  else if (bid < 2304) { W=Wo; WT=woT;                      K=768;  Nn=768;  tb=bid-1728; }
  else if (bid < 4608) { W=W1; WT=w1T;                      K=768;  Nn=3072; tb=bid-2304; }
  else                 { W=W2; WT=w2T;                      K=3072; Nn=768;  tb=bid-4608; }
  int nt = Nn >> 5;
  int bx = tb % nt, by = tb / nt;
  int tx = threadIdx.x & 31, ty = threadIdx.x >> 5;
  #pragma unroll
  for (int i = 0; i < 4; i++)
    tile[ty + i*8][tx] = W[(size_t)(by*32 + ty + i*8)*Nn + bx*32 + tx];
  __syncthreads();
  #pragma unroll
  for (int i = 0; i < 4; i++)
    WT[(size_t)(bx*32 + ty + i*8)*K + by*32 + tx] = f2bf(tile[tx][ty + i*8]);
}

__global__ __launch_bounds__(256) void concat_bias_kernel(const float* __restrict__ bq,
    const float* __restrict__ bk, const float* __restrict__ bv, float* __restrict__ bc){
  int i = blockIdx.x*256 + threadIdx.x;
  if (i >= 6*2304) return;
  int l = i / 2304, j = i % 2304;
  float v;
  if (j < 768)       v = bq[l*768 + j];
  else if (j < 1536) v = bk[l*768 + j - 768];
  else               v = bv[l*768 + j - 1536];
  bc[i] = v;
}

// ---- MFMA GEMM: R7 core (2-deep counted-vmcnt, BK=32, 32KB LDS) +
//      LDS-bounce VECTORIZED epilogue (full-cacheline stores, no write-RMW).
// C[M][ldc] = A[M][K] * BT[N][K]^T + bias.
// EPI 0: qkv (cols<1536 -> bf16 qkvb ldc=1536; cols>=1536 -> transposed bf16 VtG)
// EPI 1: bf16 + GELU;  EPI 2: f32 C += acc + bias.   K multiple of 64.
template<int EPI>
__global__ __launch_bounds__(256) void gemm_bt(const short* __restrict__ A,
    const short* __restrict__ BT, const float* __restrict__ bias,
    void* __restrict__ Cp, short* __restrict__ VtG,
    int M, int K, int ldc, int Ntiles, int nwg){
  __shared__ __align__(16) union SMem {
    struct { short A[2][128][32]; short B[2][128][32]; } k;  // 32 KB K-loop buffers
    short eh[4][16][72];                                     // epilogue bf16 bounce
    float ef[4][16][72];                                     // epilogue f32 bounce
  } sm;
  int wg = xcd_swz(blockIdx.x, nwg);
  int bm = wg / Ntiles, bn = wg % Ntiles;
  int t = threadIdx.x, lane = t & 63, w = t >> 6;
  int wm = (w >> 1)*64, wn = (w & 1)*64;
  int lr = lane & 15, lg = lane >> 4;
  int sr = lane >> 2;
  int sg = ((lane & 3) ^ ((lane >> 3) & 3)) * 8;   // inverse-swizzled source granule
  int KT = K >> 5;

  auto stage = [&](short (*Ad)[32], short (*Bd)[32], int kt){
    int k0 = kt*32;
    #pragma unroll
    for (int i = 0; i < 2; i++){
      int r = w*32 + i*16 + sr;
      int arow = bm*128 + r; if (arow >= M) arow = M-1;
      gload_lds16(A + (size_t)arow*K + k0 + sg, &Ad[w*32 + i*16][0]);
      int brow = bn*128 + r;
      gload_lds16(BT + (size_t)brow*K + k0 + sg, &Bd[w*32 + i*16][0]);
    }
  };

  f32x4 acc[4][4] = {};
  stage(sm.k.A[0], sm.k.B[0], 0);          // 4 gloads/thread in flight
  stage(sm.k.A[1], sm.k.B[1], 1);          // 8 in flight
  int rg = (lg ^ ((lr >> 1) & 3)) * 8;     // swizzled read granule

  for (int kt = 0; kt < KT; kt += 2){
    // ---- even phase ----
    asm volatile("s_waitcnt vmcnt(4)" ::: "memory");
    __builtin_amdgcn_sched_barrier(0);
    __builtin_amdgcn_s_barrier();
    {
      short8 a[4], b[4];
      #pragma unroll
      for (int m = 0; m < 4; m++) a[m] = *reinterpret_cast<const short8*>(&sm.k.A[0][wm + m*16 + lr][rg]);
      #pragma unroll
      for (int n = 0; n < 4; n++) b[n] = *reinterpret_cast<const short8*>(&sm.k.B[0][wn + n*16 + lr][rg]);
      asm volatile("s_waitcnt lgkmcnt(0)" ::: "memory");
      __builtin_amdgcn_sched_barrier(0);
      __builtin_amdgcn_s_setprio(1);
      #pragma unroll
      for (int m = 0; m < 4; m++)
        #pragma unroll
        for (int n = 0; n < 4; n++)
          acc[m][n] = __builtin_amdgcn_mfma_f32_16x16x32_bf16(a[m], b[n], acc[m][n], 0, 0, 0);
      __builtin_amdgcn_s_setprio(0);
    }
    __builtin_amdgcn_s_barrier();
    { int kn = kt + 2; if (kn > KT-1) kn = KT-1; stage(sm.k.A[0], sm.k.B[0], kn); }

    // ---- odd phase ----
    asm volatile("s_waitcnt vmcnt(4)" ::: "memory");
    __builtin_amdgcn_sched_barrier(0);
    __builtin_amdgcn_s_barrier();
    {
      short8 a[4], b[4];
      #pragma unroll
      for (int m = 0; m < 4; m++) a[m] = *reinterpret_cast<const short8*>(&sm.k.A[1][wm + m*16 + lr][rg]);
      #pragma unroll
      for (int n = 0; n < 4; n++) b[n] = *reinterpret_cast<const short8*>(&sm.k.B[1][wn + n*16 + lr][rg]);
      asm volatile("s_waitcnt lgkmcnt(0)" ::: "memory");
      __builtin_amdgcn_sched_barrier(0);
      __builtin_amdgcn_s_setprio(1);
      #pragma unroll
      for (int m = 0; m < 4; m++)
        #pragma unroll
        for (int n = 0; n < 4; n++)
          acc[m][n] = __builtin_amdgcn_mfma_f32_16x16x32_bf16(a[m], b[n], acc[m][n], 0, 0, 0);
      __builtin_amdgcn_s_setprio(0);
    }
    __builtin_amdgcn_s_barrier();
    { int kn = kt + 3; if (kn > KT-1) kn = KT-1; stage(sm.k.A[1], sm.k.B[1], kn); }
  }

  // ---- epilogue: drain staging, then LDS-bounce vectorized stores --------------
  asm volatile("s_waitcnt vmcnt(0)" ::: "memory");
  __syncthreads();

  int cbaseW = bn*128 + wn;        // wave's 64-col base
  int growW  = bm*128 + wm;        // wave's row base (+ m*16)

  if constexpr (EPI == 2){
    #pragma unroll
    for (int m = 0; m < 4; m++){
      asm volatile("s_waitcnt lgkmcnt(0)" ::: "memory");   // region free (prev m reads done)
      #pragma unroll
      for (int n = 0; n < 4; n++)
        #pragma unroll
        for (int j = 0; j < 4; j++)
          sm.ef[w][lg*4 + j][n*16 + lr] = acc[m][n][j] + bias[cbaseW + n*16 + lr];
      asm volatile("s_waitcnt lgkmcnt(0)" ::: "memory");
      #pragma unroll
      for (int cc = 0; cc < 4; cc++){
        int c = lane + cc*64;
        int row = c >> 4, seg = c & 15;
        int grow = growW + m*16 + row;
        if (grow < M){
          float* gp = (float*)Cp + (size_t)grow*ldc + cbaseW + seg*4;
          f32x4 add = *reinterpret_cast<const f32x4*>(&sm.ef[w][row][seg*4]);
          f32x4 old = *reinterpret_cast<const f32x4*>(gp);
          *reinterpret_cast<f32x4*>(gp) = old + add;
        }
      }
    }
  } else {
    bool vtg_block = (EPI == 0) && (cbaseW >= 1536);
    if (!vtg_block){
      #pragma unroll
      for (int m = 0; m < 4; m++){
        asm volatile("s_waitcnt lgkmcnt(0)" ::: "memory");
        #pragma unroll
        for (int n = 0; n < 4; n++)
          #pragma unroll
          for (int j = 0; j < 4; j++){
            float v = acc[m][n][j] + bias[cbaseW + n*16 + lr];
            if constexpr (EPI == 1) v = 0.5f*v*(1.0f + erff(v*0.70710678118654752f));
            sm.eh[w][lg*4 + j][n*16 + lr] = f2bf(v);
          }
        asm volatile("s_waitcnt lgkmcnt(0)" ::: "memory");
        #pragma unroll
        for (int cc = 0; cc < 2; cc++){
          int c = lane + cc*64;
          int row = c >> 3, seg = c & 7;
          int grow = growW + m*16 + row;
          if (grow < M)
            *reinterpret_cast<short8*>((short*)Cp + (size_t)grow*ldc + cbaseW + seg*8) =
                *reinterpret_cast<const short8*>(&sm.eh[w][row][seg*8]);
        }
      }
    } else {
      // V columns -> transposed VtG (scalar scatter; per-block uniform branch)
      #pragma unroll
      for (int m = 0; m < 4; m++){
        #pragma unroll
        for (int n = 0; n < 4; n++){
          int col = cbaseW + n*16 + lr;
          #pragma unroll
          for (int j = 0; j < 4; j++){
            int row = growW + lg*4 + m*16 + j;
            if (row < M){
              float v = acc[m][n][j] + bias[col];
              int bb = row / SP1, kp = row - bb*SP1;
              int c  = col - 1536;
              int hh = c / 96, d = c - hh*96;
              VtG[((size_t)(bb*8 + hh)*96 + d)*VTP + kp] = f2bf(v);
            }
          }
        }
      }
    }
  }
}

// ---------------- fused attention (flash, ALiBi, KVB=64, defer-max, V-prefetch) -
// qkv: [NTOK][1536] bf16 (q|k). VtG: [B*H][96][VTP] bf16. o: [NTOK][768] bf16.
__global__ __launch_bounds__(256) void attn_kernel(const short* __restrict__ qkv,
                                                   const short* __restrict__ VtG,
                                                   short* __restrict__ o){
  __shared__ __align__(16) short Plds[4][16][72];
  __shared__ __align__(16) short Vt[96][72];
  int wg = xcd_swz(blockIdx.x, 2304);
  int qt = wg % 9; int hh = (wg / 9) & 7; int b = wg / 72;
  int t = threadIdx.x, lane = t & 63, w = t >> 6;
  int lr = lane & 15, lg = lane >> 4;
  int q0 = qt*64 + w*16;
  const int RS = 1536;
  const short* base = qkv + (size_t)b*SP1*RS + hh*HD_;
  const short* kb = base + D_;
  const short* vg = VtG + (size_t)(b*8 + hh)*96*VTP;
  int qrow = q0 + lr; if (qrow > 512) qrow = 512;
  short8 qf[3];
  #pragma unroll
  for (int ks = 0; ks < 3; ks++)
    qf[ks] = *reinterpret_cast<const short8*>(base + (size_t)qrow*RS + ks*32 + lg*8);
  float m[4]    = {-1e30f, -1e30f, -1e30f, -1e30f};
  float lsum[4] = {0.f, 0.f, 0.f, 0.f};
  f32x4 oacc[6] = {};
  float slope = exp2f(-(float)(hh + 1));
  const float scale = 0.10206207261596577f;  // 1/sqrt(96)

  // V-tile register prefetch (T14): 3x short8 per thread
  short8 vv[3];
  #pragma unroll
  for (int ii = 0; ii < 3; ii++){
    int i = t + ii*256;
    vv[ii] = *reinterpret_cast<const short8*>(vg + (size_t)(i >> 3)*VTP + (i & 7)*8);
  }

  for (int t0 = 0; t0 < SP1; t0 += 64){
    bool tail = (t0 == 512);
    __syncthreads();                       // prev PV done reading Vt; Plds free
    // write current V tile from prefetched regs (LDS-only, fast)
    #pragma unroll
    for (int ii = 0; ii < 3; ii++){
      int i = t + ii*256;
      *reinterpret_cast<short8*>(&Vt[i >> 3][(i & 7)*8]) = vv[ii];
    }
    // issue next tile's V loads; they fly under QK^T + softmax
    {
      int tp = t0 + 64; if (tp > 512) tp = 512;   // clamped; unused on last iter
      #pragma unroll
      for (int ii = 0; ii < 3; ii++){
        int i = t + ii*256;
        vv[ii] = *reinterpret_cast<const short8*>(vg + (size_t)(i >> 3)*VTP + tp + (i & 7)*8);
      }
    }
    // QK^T (skip st>=1 on tail tile: keys invalid)
    f32x4 s[4] = {};
    __builtin_amdgcn_s_setprio(1);
    #pragma unroll
    for (int st = 0; st < 4; st++){
      if (st && tail) break;               // wave-uniform
      int tr = t0 + st*16 + lr; if (tr > 512) tr = 512;
      #pragma unroll
      for (int ks = 0; ks < 3; ks++){
        short8 kf = *reinterpret_cast<const short8*>(kb + (size_t)tr*RS + ks*32 + lg*8);
        s[st] = __builtin_amdgcn_mfma_f32_16x16x32_bf16(qf[ks], kf, s[st], 0, 0, 0);
      }
    }
    __builtin_amdgcn_s_setprio(0);
    // online softmax with defer-max (T13, THR=8; exact — shift cancels)
    float v[4][4]; float mxl[4]; bool need = false;
    #pragma unroll
    for (int j = 0; j < 4; j++){
      int qr = q0 + lg*4 + j;
      float mx = -3e38f;
      #pragma unroll
      for (int st = 0; st < 4; st++){
        int tc = t0 + st*16 + lr;
        float sv = (tail && st) ? -1e30f
                 : s[st][j]*scale - slope*fabsf((float)(qr - tc));
        if (tc > 512) sv = -1e30f;
        v[j][st] = sv; mx = fmaxf(mx, sv);
      }
      mxl[j] = mx;
      need |= (mx > m[j] + 8.f);
    }
    if (__any(need)){
      #pragma unroll
      for (int j = 0; j < 4; j++){
        float mx = mxl[j];
        mx = fmaxf(mx, __shfl_xor(mx, 1, 64));
        mx = fmaxf(mx, __shfl_xor(mx, 2, 64));
        mx = fmaxf(mx, __shfl_xor(mx, 4, 64));
        mx = fmaxf(mx, __shfl_xor(mx, 8, 64));
        float mn = fmaxf(m[j], mx);
        float corr = __expf(m[j] - mn);
        float rs = 0.f;
        #pragma unroll
        for (int st = 0; st < 4; st++){
          float p = __expf(v[j][st] - mn); rs += p;
          Plds[w][lg*4 + j][st*16 + lr] = f2bf(p);
        }
        rs += __shfl_xor(rs, 1, 64); rs += __shfl_xor(rs, 2, 64);
        rs += __shfl_xor(rs, 4, 64); rs += __shfl_xor(rs, 8, 64);
        lsum[j] = lsum[j]*corr + rs;
        m[j] = mn;
        #pragma unroll
        for (int n = 0; n < 6; n++) oacc[n][j] *= corr;
      }
    } else {
      #pragma unroll
      for (int j = 0; j < 4; j++){
        float rs = 0.f;
        #pragma unroll
        for (int st = 0; st < 4; st++){
          float p = __expf(v[j][st] - m[j]); rs += p;
          Plds[w][lg*4 + j][st*16 + lr] = f2bf(p);
        }
        rs += __shfl_xor(rs, 1, 64); rs += __shfl_xor(rs, 2, 64);
        rs += __shfl_xor(rs, 4, 64); rs += __shfl_xor(rs, 8, 64);
        lsum[j] += rs;
      }
    }
    __syncthreads();                       // Vt staged + Plds written
    short8 pf0 = *reinterpret_cast<const short8*>(&Plds[w][lr][lg*8]);
    __builtin_amdgcn_s_setprio(1);
    if (!tail){
      short8 pf1 = *reinterpret_cast<const short8*>(&Plds[w][lr][32 + lg*8]);
      #pragma unroll
      for (int n = 0; n < 6; n++){
        short8 vf0 = *reinterpret_cast<const short8*>(&Vt[n*16 + lr][lg*8]);
        short8 vf1 = *reinterpret_cast<const short8*>(&Vt[n*16 + lr][32 + lg*8]);
        oacc[n] = __builtin_amdgcn_mfma_f32_16x16x32_bf16(pf0, vf0, oacc[n], 0, 0, 0);
        oacc[n] = __builtin_amdgcn_mfma_f32_16x16x32_bf16(pf1, vf1, oacc[n], 0, 0, 0);
      }
    } else {
      #pragma unroll
      for (int n = 0; n < 6; n++){
        short8 vf0 = *reinterpret_cast<const short8*>(&Vt[n*16 + lr][lg*8]);
        oacc[n] = __builtin_amdgcn_mfma_f32_16x16x32_bf16(pf0, vf0, oacc[n], 0, 0, 0);
      }
    }
    __builtin_amdgcn_s_setprio(0);
  }
  #pragma unroll
  for (int j = 0; j < 4; j++){
    int qr = q0 + lg*4 + j;
    if (qr <= 512){
      float inv = 1.0f / lsum[j];
      #pragma unroll
      for (int n = 0; n < 6; n++)
        o[((size_t)b*SP1 + qr)*D_ + hh*HD_ + n*16 + lr] = f2bf(oacc[n][j]*inv);
    }
  }
}

// ---------------- head ----------------------------------------------------------
__global__ __launch_bounds__(256) void pool1_kernel(const float* __restrict__ lnfb,
                                                    float* __restrict__ part){
  int bid = blockIdx.x; int b = bid >> 3, c = bid & 7;
  int t = threadIdx.x;
  for (int d = t; d < D_; d += 256){
    const float* pb = lnfb + (size_t)b*SP1*D_ + d;
    float s = 0.f;
    for (int i = 1 + c*64; i <= (c+1)*64; i++) s += pb[(size_t)i*D_];
    part[(size_t)bid*D_ + d] = s;
  }
}

__global__ __launch_bounds__(256) void pool2_kernel(const float* __restrict__ lnfb,
    const float* __restrict__ part, float* __restrict__ pooled_in){
  int b = blockIdx.x, t = threadIdx.x;
  for (int d = t; d < D_; d += 256){
    float s = 0.f;
    #pragma unroll
    for (int c = 0; c < 8; c++) s += part[(size_t)(b*8+c)*D_ + d];
    pooled_in[b*D_ + d] = 0.5f*lnfb[(size_t)b*SP1*D_ + d] + 0.5f*(s*(1.0f/512.0f));
  }
}

__global__ __launch_bounds__(256) void matvec_kernel(const float* __restrict__ in,
    const float* __restrict__ W, const float* __restrict__ bias,
    float* __restrict__ out, int K, int Nn){
  __shared__ float inr[768];
  int nb = Nn >> 8;
  int b = blockIdx.x / nb, jc = blockIdx.x % nb;
  int t = threadIdx.x;
  for (int d = t; d < K; d += 256) inr[d] = in[(size_t)b*K + d];
  __syncthreads();
  int j = jc*256 + t;
  float acc = bias ? bias[j] : 0.0f;
  for (int d = 0; d < K; d++) acc += inr[d]*W[(size_t)d*Nn + j];
  out[(size_t)b*Nn + j] = acc;
}

__global__ __launch_bounds__(256) void norm_kernel(const float* __restrict__ c,
                                                   float* __restrict__ out){
  __shared__ float tmp[4];
  int b = blockIdx.x, t = threadIdx.x;
  float v0 = c[b*512 + t], v1 = c[b*512 + 256 + t];
  float s = block_sum256(v0*v0 + v1*v1, tmp);
  float inv = 1.0f / sqrtf(s);
  out[b*512 + t]       = v0*inv;
  out[b*512 + 256 + t] = v1*inv;
}

// ---------------- host orchestration --------------------------------------------
extern "C" void kernel_launch(void* const* d_in, const int* in_sizes, int n_in,
                              void* d_out, int out_size, void* d_ws, size_t ws_size,
                              hipStream_t stream){
  const int*   sensor_ids = (const int*)d_in[0];
  const int*   state_ids  = (const int*)d_in[1];
  const int*   room_ids   = (const int*)d_in[2];
  const float* coords     = (const float*)d_in[3];
  const float* tdelt      = (const float*)d_in[4];
  const float* emb_sensor = (const float*)d_in[6];
  const float* emb_state  = (const float*)d_in[7];
  const float* emb_room   = (const float*)d_in[8];
  const float* fourier_W  = (const float*)d_in[9];
  const float* fourier_b  = (const float*)d_in[10];
  const float* time_emb   = (const float*)d_in[11];
  const float* cls_tok    = (const float*)d_in[12];
  const float* pos_emb    = (const float*)d_in[13];
  const float* ln1_g = (const float*)d_in[14];
  const float* ln1_b = (const float*)d_in[15];
  const float* Wq = (const float*)d_in[16];
  const float* bq = (const float*)d_in[17];
  const float* Wk = (const float*)d_in[18];
  const float* bk = (const float*)d_in[19];
  const float* Wv = (const float*)d_in[20];
  const float* bv = (const float*)d_in[21];
  const float* Wo = (const float*)d_in[22];
  const float* bo = (const float*)d_in[23];
  const float* ln2_g = (const float*)d_in[24];
  const float* ln2_b = (const float*)d_in[25];
  const float* W1 = (const float*)d_in[26];
  const float* b1 = (const float*)d_in[27];
  const float* W2 = (const float*)d_in[28];
  const float* b2 = (const float*)d_in[29];
  const float* lnf_g = (const float*)d_in[30];
  const float* lnf_b = (const float*)d_in[31];
  const float* pool_W = (const float*)d_in[32];
  const float* pool_b = (const float*)d_in[33];
  const float* clip_W = (const float*)d_in[34];

  const size_t QKV_SH = (size_t)NTOK*1536;
  const size_t VTG_SH = (size_t)256*96*VTP;
  const size_t OB_SH  = (size_t)NTOK*D_;
  size_t big_bytes = (QKV_SH + VTG_SH + OB_SH)*2;

  char* p = (char*)d_ws;
  float* x       = (float*)p; p += (size_t)NTOK*D_*4;
  short* h       = (short*)p; p += (size_t)NTOK*D_*2;
  short* big     = (short*)p; p += big_bytes;
  short* wT      = (short*)p; p += (size_t)7077888*2;
  float* biascat = (float*)p; p += (size_t)6*2304*4;
  float* part      = (float*)p; p += (size_t)256*768*4;
  float* pooled_in = (float*)p; p += (size_t)32*768*4;
  float* pooled    = (float*)p; p += (size_t)32*768*4;
  float* clipv     = (float*)p; p += (size_t)32*512*4;

  short* qkvb  = big;
  short* vtg   = big + QKV_SH;
  short* ob    = vtg + VTG_SH;
  short* wqkvT = wT;                             // [2304][768]
  short* woT   = wqkvT + (size_t)2304*768;       // [768][768]
  short* w1T   = woT   + (size_t)768*768;        // [3072][768]
  short* w2T   = w1T   + (size_t)3072*768;       // [768][3072]
  float* lnfb  = (float*)big;

  embed_kernel<<<NTOK/16, 256, 0, stream>>>(sensor_ids, state_ids, room_ids, coords, tdelt,
      emb_sensor, emb_state, emb_room, fourier_W, fourier_b, time_emb, cls_tok, pos_emb, x);
  concat_bias_kernel<<<54, 256, 0, stream>>>(bq, bk, bv, biascat);

  for (int l = 0; l < 6; l++){
    transpose6_kernel<<<6912, 256, 0, stream>>>(
        Wq + (size_t)l*589824, Wk + (size_t)l*589824, Wv + (size_t)l*589824,
        Wo + (size_t)l*589824, W1 + (size_t)l*2359296, W2 + (size_t)l*2359296,
        wqkvT, woT, w1T, w2T);

    ln_kernel<short><<<NTOK, 256, 0, stream>>>(x, ln1_g + l*768, ln1_b + l*768, h);
    gemm_bt<0><<<129*18, 256, 0, stream>>>(h, wqkvT, biascat + l*2304, qkvb, vtg,
                                           NTOK, 768, 1536, 18, 129*18);
    attn_kernel<<<2304, 256, 0, stream>>>(qkvb, vtg, ob);
    gemm_bt<2><<<129*6, 256, 0, stream>>>(ob, woT, bo + l*768, x, nullptr,
                                          NTOK, 768, 768, 6, 129*6);
    ln_kernel<short><<<NTOK, 256, 0, stream>>>(x, ln2_g + l*768, ln2_b + l*768, h);
    gemm_bt<1><<<129*24, 256, 0, stream>>>(h, w1T, b1 + l*3072, big, nullptr,
                                           NTOK, 768, 3072, 24, 129*24);
    gemm_bt<2><<<129*6, 256, 0, stream>>>(big, w2T, b2 + l*768, x, nullptr,
                                          NTOK, 3072, 768, 6, 129*6);
  }

  ln_kernel<float><<<NTOK, 256, 0, stream>>>(x, lnf_g, lnf_b, lnfb);
  pool1_kernel<<<256, 256, 0, stream>>>(lnfb, part);
  pool2_kernel<<<32, 256, 0, stream>>>(lnfb, part, pooled_in);
  matvec_kernel<<<96, 256, 0, stream>>>(pooled_in, pool_W, pool_b, pooled, 768, 768);
  matvec_kernel<<<64, 256, 0, stream>>>(pooled, clip_W, nullptr, clipv, 768, 512);
  norm_kernel<<<32, 256, 0, stream>>>(clipv, (float*)d_out);
}

// Round 13
// 3692.574 us; speedup vs baseline: 1.0010x; 1.0010x over previous
//
#include <hip/hip_runtime.h>
#include <hip/hip_bf16.h>
#include <cmath>

#define B_   32
#define S_   512
#define SP1  513
#define D_   768
#define H_   8
#define HD_  96
#define L_   6
#define DFF_ 3072
#define NTOK (B_*SP1)   // 16416
#define VTP  520        // VtG padded k-stride

typedef short short8 __attribute__((ext_vector_type(8)));
typedef float f32x4  __attribute__((ext_vector_type(4)));

__device__ __forceinline__ short f2bf(float f){
  unsigned u = __float_as_uint(f);
  u += 0x7fffu + ((u >> 16) & 1u);   // RNE
  return (short)(u >> 16);
}

// bijective XCD-aware swizzle (m204)
__device__ __forceinline__ int xcd_swz(int orig, int nwg){
  int q = nwg >> 3, r = nwg & 7;
  int x = orig & 7, idx = orig >> 3;
  return (x < r ? x*(q+1) : r*(q+1) + (x-r)*q) + idx;
}

__device__ __forceinline__ void gload_lds16(const short* g, short* l){
  __builtin_amdgcn_global_load_lds((const __attribute__((address_space(1))) void*)g,
                                   (__attribute__((address_space(3))) void*)l, 16, 0, 0);
}

__device__ __forceinline__ float block_sum256(float v, float* tmp){
  #pragma unroll
  for (int o = 32; o; o >>= 1) v += __shfl_xor(v, o, 64);
  int t = threadIdx.x;
  if ((t & 63) == 0) tmp[t >> 6] = v;
  __syncthreads();
  float r = tmp[0] + tmp[1] + tmp[2] + tmp[3];
  __syncthreads();
  return r;
}

// paired reduction: one barrier pass for (sum, sumsq)
__device__ __forceinline__ void block_sum2(float& a, float& b, float* tmp){
  #pragma unroll
  for (int o = 32; o; o >>= 1){ a += __shfl_xor(a, o, 64); b += __shfl_xor(b, o, 64); }
  int t = threadIdx.x;
  if ((t & 63) == 0){ tmp[(t >> 6)*2] = a; tmp[(t >> 6)*2 + 1] = b; }
  __syncthreads();
  a = tmp[0] + tmp[2] + tmp[4] + tmp[6];
  b = tmp[1] + tmp[3] + tmp[5] + tmp[7];
  __syncthreads();
}

// ---------------- embedding -----------------------------------------------------
__global__ __launch_bounds__(256) void embed_kernel(
    const int* __restrict__ sensor_ids, const int* __restrict__ state_ids,
    const int* __restrict__ room_ids, const float* __restrict__ coords,
    const float* __restrict__ tdelt,
    const float* __restrict__ emb_sensor, const float* __restrict__ emb_state,
    const float* __restrict__ emb_room, const float* __restrict__ fourier_W,
    const float* __restrict__ fourier_b, const float* __restrict__ time_emb,
    const float* __restrict__ cls_tok, const float* __restrict__ pos_emb,
    float* __restrict__ x){
  __shared__ float ffs[16][48];
  __shared__ int meta[16][4];
  int t = threadIdx.x;
  int tok0 = blockIdx.x * 16;
  if (t < 16){
    int tk = tok0 + t;
    int b = tk / SP1, p = tk % SP1;
    int sid=0, stid=0, rid=0, tidx=0;
    if (p){
      int s = p - 1;
      sid  = sensor_ids[b*S_+s]; stid = state_ids[b*S_+s]; rid = room_ids[b*S_+s];
      float td = fmaxf(tdelt[b*S_+s], 1e-6f);
      float fi = logf(td + 1.0f) / logf(3601.0f) * 99.0f;
      int ix = (int)fi;
      tidx = ix < 0 ? 0 : (ix > 99 ? 99 : ix);
    }
    meta[t][0]=sid; meta[t][1]=stid; meta[t][2]=rid; meta[t][3]=tidx;
  }
  for (int i = t; i < 16*24; i += 256){
    int tl = i / 24, r = i % 24;
    int c = r / 12, f = r % 12;
    int tk = tok0 + tl;
    int b = tk / SP1, p = tk % SP1;
    float sv = 0.f, cv = 0.f;
    if (p){
      float ang = coords[((size_t)b*S_ + (p-1))*2 + c] * exp2f((float)f) * 3.14159265358979323846f;
      sv = sinf(ang); cv = cosf(ang);
    }
    ffs[tl][c*24 + f]      = sv;
    ffs[tl][c*24 + 12 + f] = cv;
  }
  __syncthreads();
  for (int dc = 0; dc < 3; dc++){
    int d = dc*256 + t;
    float acc[16];
    #pragma unroll
    for (int tl=0; tl<16; tl++) acc[tl] = 0.f;
    for (int f = 0; f < 48; f++){
      float wv = fourier_W[f*D_ + d];
      #pragma unroll
      for (int tl=0; tl<16; tl++) acc[tl] += ffs[tl][f] * wv;
    }
    float fb = fourier_b[d];
    for (int tl = 0; tl < 16; tl++){
      int tk = tok0 + tl;
      int b = tk / SP1, p = tk % SP1;
      float v;
      if (p == 0) v = cls_tok[d] + pos_emb[d];
      else v = emb_sensor[(size_t)meta[tl][0]*D_ + d] + emb_state[(size_t)meta[tl][1]*D_ + d]
             + emb_room[(size_t)meta[tl][2]*D_ + d] + time_emb[(size_t)meta[tl][3]*D_ + d]
             + fb + acc[tl] + pos_emb[(size_t)p*D_ + d];
      x[(size_t)tk*D_ + d] = v;
    }
  }
}

// ---------------- layernorm (one-pass mean/var) ---------------------------------
template<typename OUT>
__global__ __launch_bounds__(256) void ln_kernel(const float* __restrict__ x,
    const float* __restrict__ g, const float* __restrict__ bb, OUT* __restrict__ out){
  __shared__ float tmp[8];
  int row = blockIdx.x, t = threadIdx.x;
  const float* xr = x + (size_t)row*D_;
  float v0 = xr[t], v1 = xr[t+256], v2 = xr[t+512];
  float s1 = v0+v1+v2, s2 = v0*v0 + v1*v1 + v2*v2;
  block_sum2(s1, s2, tmp);
  float mean = s1 * (1.f/768.f);
  float var  = fmaxf(s2 * (1.f/768.f) - mean*mean, 0.f);
  float rstd = rsqrtf(var + 1e-5f);
  OUT* orow = out + (size_t)row*D_;
  float r0 = (v0-mean)*rstd*g[t]     + bb[t];
  float r1 = (v1-mean)*rstd*g[t+256] + bb[t+256];
  float r2 = (v2-mean)*rstd*g[t+512] + bb[t+512];
  if constexpr (sizeof(OUT) == 2){
    orow[t] = f2bf(r0); orow[t+256] = f2bf(r1); orow[t+512] = f2bf(r2);
  } else {
    orow[t] = r0; orow[t+256] = r1; orow[t+512] = r2;
  }
}

// ---------------- fused 6-weight transpose + f32->bf16 --------------------------
__global__ __launch_bounds__(256) void transpose6_kernel(
    const float* __restrict__ Wq, const float* __restrict__ Wk,
    const float* __restrict__ Wv, const float* __restrict__ Wo,
    const float* __restrict__ W1, const float* __restrict__ W2,
    short* __restrict__ wqkvT, short* __restrict__ woT,
    short* __restrict__ w1T, short* __restrict__ w2T){
  __shared__ float tile[32][33];
  int bid = blockIdx.x;
  const float* W; short* WT; int K, Nn, tb;
  if (bid < 576)       { W=Wq; WT=wqkvT;                    K=768;  Nn=768;  tb=bid; }
  else if (bid < 1152) { W=Wk; WT=wqkvT+(size_t)768*768;    K=768;  Nn=768;  tb=bid-576; }
  else if (bid < 1728) { W=Wv; WT=wqkvT+(size_t)1536*768;   K=768;  Nn=768;  tb=bid-1152; }
  else if (bid < 2304) { W=Wo; WT=woT;                      K=768;  Nn=768;  tb=bid-1728; }
  else if (bid < 4608) { W=W1; WT=w1T;                      K=768;  Nn=3072; tb=bid-2304; }
  else                 { W=W2; WT=w2T;                      K=3072; Nn=768;  tb=bid-4608; }
  int nt = Nn >> 5;
  int bx = tb % nt, by = tb / nt;
  int tx = threadIdx.x & 31, ty = threadIdx.x >> 5;
  #pragma unroll
  for (int i = 0; i < 4; i++)
    tile[ty + i*8][tx] = W[(size_t)(by*32 + ty + i*8)*Nn + bx*32 + tx];
  __syncthreads();
  #pragma unroll
  for (int i = 0; i < 4; i++)
    WT[(size_t)(bx*32 + ty + i*8)*K + by*32 + tx] = f2bf(tile[tx][ty + i*8]);
}

__global__ __launch_bounds__(256) void concat_bias_kernel(const float* __restrict__ bq,
    const float* __restrict__ bk, const float* __restrict__ bv, float* __restrict__ bc){
  int i = blockIdx.x*256 + threadIdx.x;
  if (i >= 6*2304) return;
  int l = i / 2304, j = i % 2304;
  float v;
  if (j < 768)       v = bq[l*768 + j];
  else if (j < 1536) v = bk[l*768 + j - 768];
  else               v = bv[l*768 + j - 1536];
  bc[i] = v;
}

// ---- MFMA GEMM: R7 core (2-deep counted-vmcnt, BK=32, 32KB LDS) +
//      LDS-bounce VECTORIZED epilogue (full-cacheline stores, no write-RMW).
// C[M][ldc] = A[M][K] * BT[N][K]^T + bias.
// EPI 0: qkv (cols<1536 -> bf16 qkvb ldc=1536; cols>=1536 -> transposed bf16 VtG)
// EPI 1: bf16 + GELU;  EPI 2: f32 C += acc + bias.   K multiple of 64.
template<int EPI>
__global__ __launch_bounds__(256) void gemm_bt(const short* __restrict__ A,
    const short* __restrict__ BT, const float* __restrict__ bias,
    void* __restrict__ Cp, short* __restrict__ VtG,
    int M, int K, int ldc, int Ntiles, int nwg){
  __shared__ __align__(16) union SMem {
    struct { short A[2][128][32]; short B[2][128][32]; } k;  // 32 KB K-loop buffers
    short eh[4][16][72];                                     // epilogue bf16 bounce
    float ef[4][16][72];                                     // epilogue f32 bounce
  } sm;
  int wg = xcd_swz(blockIdx.x, nwg);
  int bm = wg / Ntiles, bn = wg % Ntiles;
  int t = threadIdx.x, lane = t & 63, w = t >> 6;
  int wm = (w >> 1)*64, wn = (w & 1)*64;
  int lr = lane & 15, lg = lane >> 4;
  int sr = lane >> 2;
  int sg = ((lane & 3) ^ ((lane >> 3) & 3)) * 8;   // inverse-swizzled source granule
  int KT = K >> 5;

  auto stage = [&](short (*Ad)[32], short (*Bd)[32], int kt){
    int k0 = kt*32;
    #pragma unroll
    for (int i = 0; i < 2; i++){
      int r = w*32 + i*16 + sr;
      int arow = bm*128 + r; if (arow >= M) arow = M-1;
      gload_lds16(A + (size_t)arow*K + k0 + sg, &Ad[w*32 + i*16][0]);
      int brow = bn*128 + r;
      gload_lds16(BT + (size_t)brow*K + k0 + sg, &Bd[w*32 + i*16][0]);
    }
  };

  f32x4 acc[4][4] = {};
  stage(sm.k.A[0], sm.k.B[0], 0);          // 4 gloads/thread in flight
  stage(sm.k.A[1], sm.k.B[1], 1);          // 8 in flight
  int rg = (lg ^ ((lr >> 1) & 3)) * 8;     // swizzled read granule

  for (int kt = 0; kt < KT; kt += 2){
    // ---- even phase ----
    asm volatile("s_waitcnt vmcnt(4)" ::: "memory");
    __builtin_amdgcn_sched_barrier(0);
    __builtin_amdgcn_s_barrier();
    {
      short8 a[4], b[4];
      #pragma unroll
      for (int m = 0; m < 4; m++) a[m] = *reinterpret_cast<const short8*>(&sm.k.A[0][wm + m*16 + lr][rg]);
      #pragma unroll
      for (int n = 0; n < 4; n++) b[n] = *reinterpret_cast<const short8*>(&sm.k.B[0][wn + n*16 + lr][rg]);
      asm volatile("s_waitcnt lgkmcnt(0)" ::: "memory");
      __builtin_amdgcn_sched_barrier(0);
      __builtin_amdgcn_s_setprio(1);
      #pragma unroll
      for (int m = 0; m < 4; m++)
        #pragma unroll
        for (int n = 0; n < 4; n++)
          acc[m][n] = __builtin_amdgcn_mfma_f32_16x16x32_bf16(a[m], b[n], acc[m][n], 0, 0, 0);
      __builtin_amdgcn_s_setprio(0);
    }
    __builtin_amdgcn_s_barrier();
    { int kn = kt + 2; if (kn > KT-1) kn = KT-1; stage(sm.k.A[0], sm.k.B[0], kn); }

    // ---- odd phase ----
    asm volatile("s_waitcnt vmcnt(4)" ::: "memory");
    __builtin_amdgcn_sched_barrier(0);
    __builtin_amdgcn_s_barrier();
    {
      short8 a[4], b[4];
      #pragma unroll
      for (int m = 0; m < 4; m++) a[m] = *reinterpret_cast<const short8*>(&sm.k.A[1][wm + m*16 + lr][rg]);
      #pragma unroll
      for (int n = 0; n < 4; n++) b[n] = *reinterpret_cast<const short8*>(&sm.k.B[1][wn + n*16 + lr][rg]);
      asm volatile("s_waitcnt lgkmcnt(0)" ::: "memory");
      __builtin_amdgcn_sched_barrier(0);
      __builtin_amdgcn_s_setprio(1);
      #pragma unroll
      for (int m = 0; m < 4; m++)
        #pragma unroll
        for (int n = 0; n < 4; n++)
          acc[m][n] = __builtin_amdgcn_mfma_f32_16x16x32_bf16(a[m], b[n], acc[m][n], 0, 0, 0);
      __builtin_amdgcn_s_setprio(0);
    }
    __builtin_amdgcn_s_barrier();
    { int kn = kt + 3; if (kn > KT-1) kn = KT-1; stage(sm.k.A[1], sm.k.B[1], kn); }
  }

  // ---- epilogue: drain staging, then LDS-bounce vectorized stores --------------
  asm volatile("s_waitcnt vmcnt(0)" ::: "memory");
  __syncthreads();

  int cbaseW = bn*128 + wn;        // wave's 64-col base
  int growW  = bm*128 + wm;        // wave's row base (+ m*16)

  if constexpr (EPI == 2){
    #pragma unroll
    for (int m = 0; m < 4; m++){
      asm volatile("s_waitcnt lgkmcnt(0)" ::: "memory");   // region free (prev m reads done)
      #pragma unroll
      for (int n = 0; n < 4; n++)
        #pragma unroll
        for (int j = 0; j < 4; j++)
          sm.ef[w][lg*4 + j][n*16 + lr] = acc[m][n][j] + bias[cbaseW + n*16 + lr];
      asm volatile("s_waitcnt lgkmcnt(0)" ::: "memory");
      #pragma unroll
      for (int cc = 0; cc < 4; cc++){
        int c = lane + cc*64;
        int row = c >> 4, seg = c & 15;
        int grow = growW + m*16 + row;
        if (grow < M){
          float* gp = (float*)Cp + (size_t)grow*ldc + cbaseW + seg*4;
          f32x4 add = *reinterpret_cast<const f32x4*>(&sm.ef[w][row][seg*4]);
          f32x4 old = *reinterpret_cast<const f32x4*>(gp);
          *reinterpret_cast<f32x4*>(gp) = old + add;
        }
      }
    }
  } else {
    bool vtg_block = (EPI == 0) && (cbaseW >= 1536);
    if (!vtg_block){
      #pragma unroll
      for (int m = 0; m < 4; m++){
        asm volatile("s_waitcnt lgkmcnt(0)" ::: "memory");
        #pragma unroll
        for (int n = 0; n < 4; n++)
          #pragma unroll
          for (int j = 0; j < 4; j++){
            float v = acc[m][n][j] + bias[cbaseW + n*16 + lr];
            if constexpr (EPI == 1) v = 0.5f*v*(1.0f + erff(v*0.70710678118654752f));
            sm.eh[w][lg*4 + j][n*16 + lr] = f2bf(v);
          }
        asm volatile("s_waitcnt lgkmcnt(0)" ::: "memory");
        #pragma unroll
        for (int cc = 0; cc < 2; cc++){
          int c = lane + cc*64;
          int row = c >> 3, seg = c & 7;
          int grow = growW + m*16 + row;
          if (grow < M)
            *reinterpret_cast<short8*>((short*)Cp + (size_t)grow*ldc + cbaseW + seg*8) =
                *reinterpret_cast<const short8*>(&sm.eh[w][row][seg*8]);
        }
      }
    } else {
      // V columns -> transposed VtG (scalar scatter; per-block uniform branch)
      #pragma unroll
      for (int m = 0; m < 4; m++){
        #pragma unroll
        for (int n = 0; n < 4; n++){
          int col = cbaseW + n*16 + lr;
          #pragma unroll
          for (int j = 0; j < 4; j++){
            int row = growW + lg*4 + m*16 + j;
            if (row < M){
              float v = acc[m][n][j] + bias[col];
              int bb = row / SP1, kp = row - bb*SP1;
              int c  = col - 1536;
              int hh = c / 96, d = c - hh*96;
              VtG[((size_t)(bb*8 + hh)*96 + d)*VTP + kp] = f2bf(v);
            }
          }
        }
      }
    }
  }
}

// ------- fused attention (flash, ALiBi, KVB=64, K+V reg-prefetch, tail-skip) ----
// qkv: [NTOK][1536] bf16 (q|k). VtG: [B*H][96][VTP] bf16. o: [NTOK][768] bf16.
__global__ __launch_bounds__(256) void attn_kernel(const short* __restrict__ qkv,
                                                   const short* __restrict__ VtG,
                                                   short* __restrict__ o){
  __shared__ __align__(16) short Plds[4][16][72];
  __shared__ __align__(16) short Vt[96][72];
  int wg = xcd_swz(blockIdx.x, 2304);
  int qt = wg % 9; int hh = (wg / 9) & 7; int b = wg / 72;
  int t = threadIdx.x, lane = t & 63, w = t >> 6;
  int lr = lane & 15, lg = lane >> 4;
  int q0 = qt*64 + w*16;
  const int RS = 1536;
  const short* base = qkv + (size_t)b*SP1*RS + hh*HD_;
  const short* kb = base + D_;
  const short* vg = VtG + (size_t)(b*8 + hh)*96*VTP;
  int qrow = q0 + lr; if (qrow > 512) qrow = 512;
  short8 qf[3];
  #pragma unroll
  for (int ks = 0; ks < 3; ks++)
    qf[ks] = *reinterpret_cast<const short8*>(base + (size_t)qrow*RS + ks*32 + lg*8);
  float m[4]    = {-1e30f, -1e30f, -1e30f, -1e30f};
  float lsum[4] = {0.f, 0.f, 0.f, 0.f};
  f32x4 oacc[6] = {};
  float slope = exp2f(-(float)(hh + 1));
  const float scale = 0.10206207261596577f;  // 1/sqrt(96)

  // V-tile register prefetch: 3x short8
  short8 vv[3];
  #pragma unroll
  for (int ii = 0; ii < 3; ii++){
    int i = t + ii*256;
    vv[ii] = *reinterpret_cast<const short8*>(vg + (size_t)(i >> 3)*VTP + (i & 7)*8);
  }
  // K-fragment register prefetch (single-buffered, 12x short8 = 48 VGPR)
  short8 kff[4][3];
  #pragma unroll
  for (int st = 0; st < 4; st++){
    int tr = st*16 + lr;
    #pragma unroll
    for (int ks = 0; ks < 3; ks++)
      kff[st][ks] = *reinterpret_cast<const short8*>(kb + (size_t)tr*RS + ks*32 + lg*8);
  }

  for (int t0 = 0; t0 < SP1; t0 += 64){
    bool tail = (t0 == 512);
    __syncthreads();                       // prev PV done reading Vt; Plds free
    // write current V tile from prefetched regs
    #pragma unroll
    for (int ii = 0; ii < 3; ii++){
      int i = t + ii*256;
      *reinterpret_cast<short8*>(&Vt[i >> 3][(i & 7)*8]) = vv[ii];
    }
    // issue next tile's V loads (fly under QK^T + softmax + PV)
    {
      int tp = t0 + 64; if (tp > 512) tp = 512;
      #pragma unroll
      for (int ii = 0; ii < 3; ii++){
        int i = t + ii*256;
        vv[ii] = *reinterpret_cast<const short8*>(vg + (size_t)(i >> 3)*VTP + tp + (i & 7)*8);
      }
    }
    // QK^T: pure MFMA burst from prefetched kff (skip st>=1 on tail tile)
    f32x4 s[4] = {};
    __builtin_amdgcn_s_setprio(1);
    #pragma unroll
    for (int st = 0; st < 4; st++){
      if (st && tail) break;               // wave-uniform
      #pragma unroll
      for (int ks = 0; ks < 3; ks++)
        s[st] = __builtin_amdgcn_mfma_f32_16x16x32_bf16(qf[ks], kff[st][ks], s[st], 0, 0, 0);
    }
    __builtin_amdgcn_s_setprio(0);
    // re-issue kff loads for NEXT tile (regs just consumed; loads fly under
    // softmax + barrier + PV ≈ 800+ cy)
    {
      int tn = t0 + 64; if (tn > 512) tn = 512;
      #pragma unroll
      for (int st = 0; st < 4; st++){
        int tr = tn + st*16 + lr; if (tr > 512) tr = 512;
        #pragma unroll
        for (int ks = 0; ks < 3; ks++)
          kff[st][ks] = *reinterpret_cast<const short8*>(kb + (size_t)tr*RS + ks*32 + lg*8);
      }
    }
    __builtin_amdgcn_sched_barrier(0);     // pin load-issue point
    // online softmax (R11 always-rescale form)
    #pragma unroll
    for (int j = 0; j < 4; j++){
      int qr = q0 + lg*4 + j;
      float v[4]; float mx = -1e30f;
      #pragma unroll
      for (int st = 0; st < 4; st++){
        int tc = t0 + st*16 + lr;
        float sv = (tail && st) ? -1e30f
                 : s[st][j]*scale - slope*fabsf((float)(qr - tc));
        if (tc > 512) sv = -1e30f;
        v[st] = sv; mx = fmaxf(mx, sv);
      }
      mx = fmaxf(mx, __shfl_xor(mx, 1, 64));
      mx = fmaxf(mx, __shfl_xor(mx, 2, 64));
      mx = fmaxf(mx, __shfl_xor(mx, 4, 64));
      mx = fmaxf(mx, __shfl_xor(mx, 8, 64));
      float mn = fmaxf(m[j], mx);
      float corr = __expf(m[j] - mn);
      float rs = 0.f;
      #pragma unroll
      for (int st = 0; st < 4; st++){
        float p = __expf(v[st] - mn); rs += p;
        Plds[w][lg*4 + j][st*16 + lr] = f2bf(p);
      }
      rs += __shfl_xor(rs, 1, 64); rs += __shfl_xor(rs, 2, 64);
      rs += __shfl_xor(rs, 4, 64); rs += __shfl_xor(rs, 8, 64);
      lsum[j] = lsum[j]*corr + rs;
      m[j] = mn;
      #pragma unroll
      for (int n = 0; n < 6; n++) oacc[n][j] *= corr;
    }
    __syncthreads();                       // Vt staged + Plds written
    short8 pf0 = *reinterpret_cast<const short8*>(&Plds[w][lr][lg*8]);
    __builtin_amdgcn_s_setprio(1);
    if (!tail){
      short8 pf1 = *reinterpret_cast<const short8*>(&Plds[w][lr][32 + lg*8]);
      #pragma unroll
      for (int n = 0; n < 6; n++){
        short8 vf0 = *reinterpret_cast<const short8*>(&Vt[n*16 + lr][lg*8]);
        short8 vf1 = *reinterpret_cast<const short8*>(&Vt[n*16 + lr][32 + lg*8]);
        oacc[n] = __builtin_amdgcn_mfma_f32_16x16x32_bf16(pf0, vf0, oacc[n], 0, 0, 0);
        oacc[n] = __builtin_amdgcn_mfma_f32_16x16x32_bf16(pf1, vf1, oacc[n], 0, 0, 0);
      }
    } else {
      #pragma unroll
      for (int n = 0; n < 6; n++){
        short8 vf0 = *reinterpret_cast<const short8*>(&Vt[n*16 + lr][lg*8]);
        oacc[n] = __builtin_amdgcn_mfma_f32_16x16x32_bf16(pf0, vf0, oacc[n], 0, 0, 0);
      }
    }
    __builtin_amdgcn_s_setprio(0);
  }
  #pragma unroll
  for (int j = 0; j < 4; j++){
    int qr = q0 + lg*4 + j;
    if (qr <= 512){
      float inv = 1.0f / lsum[j];
      #pragma unroll
      for (int n = 0; n < 6; n++)
        o[((size_t)b*SP1 + qr)*D_ + hh*HD_ + n*16 + lr] = f2bf(oacc[n][j]*inv);
    }
  }
}

// ---------------- head ----------------------------------------------------------
__global__ __launch_bounds__(256) void pool1_kernel(const float* __restrict__ lnfb,
                                                    float* __restrict__ part){
  int bid = blockIdx.x; int b = bid >> 3, c = bid & 7;
  int t = threadIdx.x;
  for (int d = t; d < D_; d += 256){
    const float* pb = lnfb + (size_t)b*SP1*D_ + d;
    float s = 0.f;
    for (int i = 1 + c*64; i <= (c+1)*64; i++) s += pb[(size_t)i*D_];
    part[(size_t)bid*D_ + d] = s;
  }
}

__global__ __launch_bounds__(256) void pool2_kernel(const float* __restrict__ lnfb,
    const float* __restrict__ part, float* __restrict__ pooled_in){
  int b = blockIdx.x, t = threadIdx.x;
  for (int d = t; d < D_; d += 256){
    float s = 0.f;
    #pragma unroll
    for (int c = 0; c < 8; c++) s += part[(size_t)(b*8+c)*D_ + d];
    pooled_in[b*D_ + d] = 0.5f*lnfb[(size_t)b*SP1*D_ + d] + 0.5f*(s*(1.0f/512.0f));
  }
}

__global__ __launch_bounds__(256) void matvec_kernel(const float* __restrict__ in,
    const float* __restrict__ W, const float* __restrict__ bias,
    float* __restrict__ out, int K, int Nn){
  __shared__ float inr[768];
  int nb = Nn >> 8;
  int b = blockIdx.x / nb, jc = blockIdx.x % nb;
  int t = threadIdx.x;
  for (int d = t; d < K; d += 256) inr[d] = in[(size_t)b*K + d];
  __syncthreads();
  int j = jc*256 + t;
  float acc = bias ? bias[j] : 0.0f;
  for (int d = 0; d < K; d++) acc += inr[d]*W[(size_t)d*Nn + j];
  out[(size_t)b*Nn + j] = acc;
}

__global__ __launch_bounds__(256) void norm_kernel(const float* __restrict__ c,
                                                   float* __restrict__ out){
  __shared__ float tmp[4];
  int b = blockIdx.x, t = threadIdx.x;
  float v0 = c[b*512 + t], v1 = c[b*512 + 256 + t];
  float s = block_sum256(v0*v0 + v1*v1, tmp);
  float inv = 1.0f / sqrtf(s);
  out[b*512 + t]       = v0*inv;
  out[b*512 + 256 + t] = v1*inv;
}

// ---------------- host orchestration --------------------------------------------
extern "C" void kernel_launch(void* const* d_in, const int* in_sizes, int n_in,
                              void* d_out, int out_size, void* d_ws, size_t ws_size,
                              hipStream_t stream){
  const int*   sensor_ids = (const int*)d_in[0];
  const int*   state_ids  = (const int*)d_in[1];
  const int*   room_ids   = (const int*)d_in[2];
  const float* coords     = (const float*)d_in[3];
  const float* tdelt      = (const float*)d_in[4];
  const float* emb_sensor = (const float*)d_in[6];
  const float* emb_state  = (const float*)d_in[7];
  const float* emb_room   = (const float*)d_in[8];
  const float* fourier_W  = (const float*)d_in[9];
  const float* fourier_b  = (const float*)d_in[10];
  const float* time_emb   = (const float*)d_in[11];
  const float* cls_tok    = (const float*)d_in[12];
  const float* pos_emb    = (const float*)d_in[13];
  const float* ln1_g = (const float*)d_in[14];
  const float* ln1_b = (const float*)d_in[15];
  const float* Wq = (const float*)d_in[16];
  const float* bq = (const float*)d_in[17];
  const float* Wk = (const float*)d_in[18];
  const float* bk = (const float*)d_in[19];
  const float* Wv = (const float*)d_in[20];
  const float* bv = (const float*)d_in[21];
  const float* Wo = (const float*)d_in[22];
  const float* bo = (const float*)d_in[23];
  const float* ln2_g = (const float*)d_in[24];
  const float* ln2_b = (const float*)d_in[25];
  const float* W1 = (const float*)d_in[26];
  const float* b1 = (const float*)d_in[27];
  const float* W2 = (const float*)d_in[28];
  const float* b2 = (const float*)d_in[29];
  const float* lnf_g = (const float*)d_in[30];
  const float* lnf_b = (const float*)d_in[31];
  const float* pool_W = (const float*)d_in[32];
  const float* pool_b = (const float*)d_in[33];
  const float* clip_W = (const float*)d_in[34];

  const size_t QKV_SH = (size_t)NTOK*1536;
  const size_t VTG_SH = (size_t)256*96*VTP;
  const size_t OB_SH  = (size_t)NTOK*D_;
  size_t big_bytes = (QKV_SH + VTG_SH + OB_SH)*2;

  char* p = (char*)d_ws;
  float* x       = (float*)p; p += (size_t)NTOK*D_*4;
  short* h       = (short*)p; p += (size_t)NTOK*D_*2;
  short* big     = (short*)p; p += big_bytes;
  short* wT      = (short*)p; p += (size_t)7077888*2;
  float* biascat = (float*)p; p += (size_t)6*2304*4;
  float* part      = (float*)p; p += (size_t)256*768*4;
  float* pooled_in = (float*)p; p += (size_t)32*768*4;
  float* pooled    = (float*)p; p += (size_t)32*768*4;
  float* clipv     = (float*)p; p += (size_t)32*512*4;

  short* qkvb  = big;
  short* vtg   = big + QKV_SH;
  short* ob    = vtg + VTG_SH;
  short* wqkvT = wT;                             // [2304][768]
  short* woT   = wqkvT + (size_t)2304*768;       // [768][768]
  short* w1T   = woT   + (size_t)768*768;        // [3072][768]
  short* w2T   = w1T   + (size_t)3072*768;       // [768][3072]
  float* lnfb  = (float*)big;

  embed_kernel<<<NTOK/16, 256, 0, stream>>>(sensor_ids, state_ids, room_ids, coords, tdelt,
      emb_sensor, emb_state, emb_room, fourier_W, fourier_b, time_emb, cls_tok, pos_emb, x);
  concat_bias_kernel<<<54, 256, 0, stream>>>(bq, bk, bv, biascat);

  for (int l = 0; l < 6; l++){
    transpose6_kernel<<<6912, 256, 0, stream>>>(
        Wq + (size_t)l*589824, Wk + (size_t)l*589824, Wv + (size_t)l*589824,
        Wo + (size_t)l*589824, W1 + (size_t)l*2359296, W2 + (size_t)l*2359296,
        wqkvT, woT, w1T, w2T);

    ln_kernel<short><<<NTOK, 256, 0, stream>>>(x, ln1_g + l*768, ln1_b + l*768, h);
    gemm_bt<0><<<129*18, 256, 0, stream>>>(h, wqkvT, biascat + l*2304, qkvb, vtg,
                                           NTOK, 768, 1536, 18, 129*18);
    attn_kernel<<<2304, 256, 0, stream>>>(qkvb, vtg, ob);
    gemm_bt<2><<<129*6, 256, 0, stream>>>(ob, woT, bo + l*768, x, nullptr,
                                          NTOK, 768, 768, 6, 129*6);
    ln_kernel<short><<<NTOK, 256, 0, stream>>>(x, ln2_g + l*768, ln2_b + l*768, h);
    gemm_bt<1><<<129*24, 256, 0, stream>>>(h, w1T, b1 + l*3072, big, nullptr,
                                           NTOK, 768, 3072, 24, 129*24);
    gemm_bt<2><<<129*6, 256, 0, stream>>>(big, w2T, b2 + l*768, x, nullptr,
                                          NTOK, 3072, 768, 6, 129*6);
  }

  ln_kernel<float><<<NTOK, 256, 0, stream>>>(x, lnf_g, lnf_b, lnfb);
  pool1_kernel<<<256, 256, 0, stream>>>(lnfb, part);
  pool2_kernel<<<32, 256, 0, stream>>>(lnfb, part, pooled_in);
  matvec_kernel<<<96, 256, 0, stream>>>(pooled_in, pool_W, pool_b, pooled, 768, 768);
  matvec_kernel<<<64, 256, 0, stream>>>(pooled, clip_W, nullptr, clipv, 768, 512);
  norm_kernel<<<32, 256, 0, stream>>>(clipv, (float*)d_out);
}

// Round 15
// 3650.420 us; speedup vs baseline: 1.0125x; 1.0115x over previous
//
#include <hip/hip_runtime.h>
#include <hip/hip_bf16.h>
#include <cmath>

#define B_   32
#define S_   512
#define SP1  513
#define D_   768
#define H_   8
#define HD_  96
#define L_   6
#define DFF_ 3072
#define NTOK (B_*SP1)   // 16416
#define VTP  520        // VtG padded k-stride

typedef short s16x4  __attribute__((ext_vector_type(4)));
typedef short short8 __attribute__((ext_vector_type(8)));
typedef float f32x4  __attribute__((ext_vector_type(4)));

__device__ __forceinline__ short f2bf(float f){
  unsigned u = __float_as_uint(f);
  u += 0x7fffu + ((u >> 16) & 1u);   // RNE
  return (short)(u >> 16);
}

// bijective XCD-aware swizzle (m204)
__device__ __forceinline__ int xcd_swz(int orig, int nwg){
  int q = nwg >> 3, r = nwg & 7;
  int x = orig & 7, idx = orig >> 3;
  return (x < r ? x*(q+1) : r*(q+1) + (x-r)*q) + idx;
}

__device__ __forceinline__ void gload_lds16(const short* g, short* l){
  __builtin_amdgcn_global_load_lds((const __attribute__((address_space(1))) void*)g,
                                   (__attribute__((address_space(3))) void*)l, 16, 0, 0);
}

__device__ __forceinline__ float block_sum256(float v, float* tmp){
  #pragma unroll
  for (int o = 32; o; o >>= 1) v += __shfl_xor(v, o, 64);
  int t = threadIdx.x;
  if ((t & 63) == 0) tmp[t >> 6] = v;
  __syncthreads();
  float r = tmp[0] + tmp[1] + tmp[2] + tmp[3];
  __syncthreads();
  return r;
}

// ---------------- embedding -----------------------------------------------------
__global__ __launch_bounds__(256) void embed_kernel(
    const int* __restrict__ sensor_ids, const int* __restrict__ state_ids,
    const int* __restrict__ room_ids, const float* __restrict__ coords,
    const float* __restrict__ tdelt,
    const float* __restrict__ emb_sensor, const float* __restrict__ emb_state,
    const float* __restrict__ emb_room, const float* __restrict__ fourier_W,
    const float* __restrict__ fourier_b, const float* __restrict__ time_emb,
    const float* __restrict__ cls_tok, const float* __restrict__ pos_emb,
    float* __restrict__ x){
  __shared__ float ffs[16][48];
  __shared__ int meta[16][4];
  int t = threadIdx.x;
  int tok0 = blockIdx.x * 16;
  if (t < 16){
    int tk = tok0 + t;
    int b = tk / SP1, p = tk % SP1;
    int sid=0, stid=0, rid=0, tidx=0;
    if (p){
      int s = p - 1;
      sid  = sensor_ids[b*S_+s]; stid = state_ids[b*S_+s]; rid = room_ids[b*S_+s];
      float td = fmaxf(tdelt[b*S_+s], 1e-6f);
      float fi = logf(td + 1.0f) / logf(3601.0f) * 99.0f;
      int ix = (int)fi;
      tidx = ix < 0 ? 0 : (ix > 99 ? 99 : ix);
    }
    meta[t][0]=sid; meta[t][1]=stid; meta[t][2]=rid; meta[t][3]=tidx;
  }
  for (int i = t; i < 16*24; i += 256){
    int tl = i / 24, r = i % 24;
    int c = r / 12, f = r % 12;
    int tk = tok0 + tl;
    int b = tk / SP1, p = tk % SP1;
    float sv = 0.f, cv = 0.f;
    if (p){
      float ang = coords[((size_t)b*S_ + (p-1))*2 + c] * exp2f((float)f) * 3.14159265358979323846f;
      sv = sinf(ang); cv = cosf(ang);
    }
    ffs[tl][c*24 + f]      = sv;
    ffs[tl][c*24 + 12 + f] = cv;
  }
  __syncthreads();
  for (int dc = 0; dc < 3; dc++){
    int d = dc*256 + t;
    float acc[16];
    #pragma unroll
    for (int tl=0; tl<16; tl++) acc[tl] = 0.f;
    for (int f = 0; f < 48; f++){
      float wv = fourier_W[f*D_ + d];
      #pragma unroll
      for (int tl=0; tl<16; tl++) acc[tl] += ffs[tl][f] * wv;
    }
    float fb = fourier_b[d];
    for (int tl = 0; tl < 16; tl++){
      int tk = tok0 + tl;
      int b = tk / SP1, p = tk % SP1;
      float v;
      if (p == 0) v = cls_tok[d] + pos_emb[d];
      else v = emb_sensor[(size_t)meta[tl][0]*D_ + d] + emb_state[(size_t)meta[tl][1]*D_ + d]
             + emb_room[(size_t)meta[tl][2]*D_ + d] + time_emb[(size_t)meta[tl][3]*D_ + d]
             + fb + acc[tl] + pos_emb[(size_t)p*D_ + d];
      x[(size_t)tk*D_ + d] = v;
    }
  }
}

// ---------------- layernorm: wave-per-row, shuffle-only, vectorized -------------
// 4 rows per 256-thread block; each row owned by one wave (64 lanes x 12 f32).
template<typename OUT>
__global__ __launch_bounds__(256) void ln_kernel(const float* __restrict__ x,
    const float* __restrict__ g, const float* __restrict__ bb, OUT* __restrict__ out){
  int lane = threadIdx.x & 63, w = threadIdx.x >> 6;
  int row = blockIdx.x*4 + w;
  const float* xr = x + (size_t)row*D_;
  f32x4 v[3];
  float s1 = 0.f, s2 = 0.f;
  #pragma unroll
  for (int k = 0; k < 3; k++){
    v[k] = *reinterpret_cast<const f32x4*>(xr + lane*4 + k*256);
    #pragma unroll
    for (int e = 0; e < 4; e++){ s1 += v[k][e]; s2 += v[k][e]*v[k][e]; }
  }
  #pragma unroll
  for (int o = 32; o; o >>= 1){
    s1 += __shfl_xor(s1, o, 64); s2 += __shfl_xor(s2, o, 64);
  }
  float mean = s1 * (1.f/768.f);
  float var  = fmaxf(s2 * (1.f/768.f) - mean*mean, 0.f);
  float rstd = rsqrtf(var + 1e-5f);
  OUT* orow = out + (size_t)row*D_;
  #pragma unroll
  for (int k = 0; k < 3; k++){
    int c0 = lane*4 + k*256;
    f32x4 gv = *reinterpret_cast<const f32x4*>(g + c0);
    f32x4 bv = *reinterpret_cast<const f32x4*>(bb + c0);
    if constexpr (sizeof(OUT) == 2){
      s16x4 r;
      #pragma unroll
      for (int e = 0; e < 4; e++) r[e] = f2bf((v[k][e]-mean)*rstd*gv[e] + bv[e]);
      *reinterpret_cast<s16x4*>((short*)orow + c0) = r;
    } else {
      f32x4 r;
      #pragma unroll
      for (int e = 0; e < 4; e++) r[e] = (v[k][e]-mean)*rstd*gv[e] + bv[e];
      *reinterpret_cast<f32x4*>((float*)orow + c0) = r;
    }
  }
}

// ------- fused 6-weight transpose + f32->bf16, full-cacheline short8 writes -----
// Per block: 64(K-rows) x 32(N-cols) of W -> 32 output rows x 64 bf16 (128B lines)
__global__ __launch_bounds__(256) void transpose6_kernel(
    const float* __restrict__ Wq, const float* __restrict__ Wk,
    const float* __restrict__ Wv, const float* __restrict__ Wo,
    const float* __restrict__ W1, const float* __restrict__ W2,
    short* __restrict__ wqkvT, short* __restrict__ woT,
    short* __restrict__ w1T, short* __restrict__ w2T){
  __shared__ float tileT[32][65];
  int bid = blockIdx.x;
  const float* W; short* WT; int K, Nn, tb;
  if (bid < 288)       { W=Wq; WT=wqkvT;                    K=768;  Nn=768;  tb=bid; }
  else if (bid < 576)  { W=Wk; WT=wqkvT+(size_t)768*768;    K=768;  Nn=768;  tb=bid-288; }
  else if (bid < 864)  { W=Wv; WT=wqkvT+(size_t)1536*768;   K=768;  Nn=768;  tb=bid-576; }
  else if (bid < 1152) { W=Wo; WT=woT;                      K=768;  Nn=768;  tb=bid-864; }
  else if (bid < 2304) { W=W1; WT=w1T;                      K=768;  Nn=3072; tb=bid-1152; }
  else                 { W=W2; WT=w2T;                      K=3072; Nn=768;  tb=bid-2304; }
  int nt = Nn >> 5;                 // N-tiles of 32
  int bx = tb % nt, by = tb / nt;   // by: 64-row K-tile
  int t = threadIdx.x;
  int lc = t & 31, lrw = t >> 5;    // load: col 0..31, row-group 0..7
  #pragma unroll
  for (int i = 0; i < 8; i++)
    tileT[lc][i*8 + lrw] = W[(size_t)(by*64 + i*8 + lrw)*Nn + bx*32 + lc];
  __syncthreads();
  int r = t >> 3, seg = t & 7;      // write: out-row 0..31, 8-col segment
  short8 o8;
  #pragma unroll
  for (int q = 0; q < 8; q++) o8[q] = f2bf(tileT[r][seg*8 + q]);
  *reinterpret_cast<short8*>(WT + (size_t)(bx*32 + r)*K + by*64 + seg*8) = o8;
}

__global__ __launch_bounds__(256) void concat_bias_kernel(const float* __restrict__ bq,
    const float* __restrict__ bk, const float* __restrict__ bv, float* __restrict__ bc){
  int i = blockIdx.x*256 + threadIdx.x;
  if (i >= 6*2304) return;
  int l = i / 2304, j = i % 2304;
  float v;
  if (j < 768)       v = bq[l*768 + j];
  else if (j < 1536) v = bk[l*768 + j - 768];
  else               v = bv[l*768 + j - 1536];
  bc[i] = v;
}

// ---- MFMA GEMM: R7 core (2-deep counted-vmcnt, BK=32, 32KB LDS) +
//      LDS-bounce VECTORIZED epilogue (full-cacheline stores, no write-RMW).
template<int EPI>
__global__ __launch_bounds__(256) void gemm_bt(const short* __restrict__ A,
    const short* __restrict__ BT, const float* __restrict__ bias,
    void* __restrict__ Cp, short* __restrict__ VtG,
    int M, int K, int ldc, int Ntiles, int nwg){
  __shared__ __align__(16) union SMem {
    struct { short A[2][128][32]; short B[2][128][32]; } k;  // 32 KB K-loop buffers
    short eh[4][16][72];                                     // epilogue bf16 bounce
    float ef[4][16][72];                                     // epilogue f32 bounce
  } sm;
  int wg = xcd_swz(blockIdx.x, nwg);
  int bm = wg / Ntiles, bn = wg % Ntiles;
  int t = threadIdx.x, lane = t & 63, w = t >> 6;
  int wm = (w >> 1)*64, wn = (w & 1)*64;
  int lr = lane & 15, lg = lane >> 4;
  int sr = lane >> 2;
  int sg = ((lane & 3) ^ ((lane >> 3) & 3)) * 8;   // inverse-swizzled source granule
  int KT = K >> 5;

  auto stage = [&](short (*Ad)[32], short (*Bd)[32], int kt){
    int k0 = kt*32;
    #pragma unroll
    for (int i = 0; i < 2; i++){
      int r = w*32 + i*16 + sr;
      int arow = bm*128 + r; if (arow >= M) arow = M-1;
      gload_lds16(A + (size_t)arow*K + k0 + sg, &Ad[w*32 + i*16][0]);
      int brow = bn*128 + r;
      gload_lds16(BT + (size_t)brow*K + k0 + sg, &Bd[w*32 + i*16][0]);
    }
  };

  f32x4 acc[4][4] = {};
  stage(sm.k.A[0], sm.k.B[0], 0);
  stage(sm.k.A[1], sm.k.B[1], 1);
  int rg = (lg ^ ((lr >> 1) & 3)) * 8;

  for (int kt = 0; kt < KT; kt += 2){
    asm volatile("s_waitcnt vmcnt(4)" ::: "memory");
    __builtin_amdgcn_sched_barrier(0);
    __builtin_amdgcn_s_barrier();
    {
      short8 a[4], b[4];
      #pragma unroll
      for (int m = 0; m < 4; m++) a[m] = *reinterpret_cast<const short8*>(&sm.k.A[0][wm + m*16 + lr][rg]);
      #pragma unroll
      for (int n = 0; n < 4; n++) b[n] = *reinterpret_cast<const short8*>(&sm.k.B[0][wn + n*16 + lr][rg]);
      asm volatile("s_waitcnt lgkmcnt(0)" ::: "memory");
      __builtin_amdgcn_sched_barrier(0);
      __builtin_amdgcn_s_setprio(1);
      #pragma unroll
      for (int m = 0; m < 4; m++)
        #pragma unroll
        for (int n = 0; n < 4; n++)
          acc[m][n] = __builtin_amdgcn_mfma_f32_16x16x32_bf16(a[m], b[n], acc[m][n], 0, 0, 0);
      __builtin_amdgcn_s_setprio(0);
    }
    __builtin_amdgcn_s_barrier();
    { int kn = kt + 2; if (kn > KT-1) kn = KT-1; stage(sm.k.A[0], sm.k.B[0], kn); }

    asm volatile("s_waitcnt vmcnt(4)" ::: "memory");
    __builtin_amdgcn_sched_barrier(0);
    __builtin_amdgcn_s_barrier();
    {
      short8 a[4], b[4];
      #pragma unroll
      for (int m = 0; m < 4; m++) a[m] = *reinterpret_cast<const short8*>(&sm.k.A[1][wm + m*16 + lr][rg]);
      #pragma unroll
      for (int n = 0; n < 4; n++) b[n] = *reinterpret_cast<const short8*>(&sm.k.B[1][wn + n*16 + lr][rg]);
      asm volatile("s_waitcnt lgkmcnt(0)" ::: "memory");
      __builtin_amdgcn_sched_barrier(0);
      __builtin_amdgcn_s_setprio(1);
      #pragma unroll
      for (int m = 0; m < 4; m++)
        #pragma unroll
        for (int n = 0; n < 4; n++)
          acc[m][n] = __builtin_amdgcn_mfma_f32_16x16x32_bf16(a[m], b[n], acc[m][n], 0, 0, 0);
      __builtin_amdgcn_s_setprio(0);
    }
    __builtin_amdgcn_s_barrier();
    { int kn = kt + 3; if (kn > KT-1) kn = KT-1; stage(sm.k.A[1], sm.k.B[1], kn); }
  }

  asm volatile("s_waitcnt vmcnt(0)" ::: "memory");
  __syncthreads();

  int cbaseW = bn*128 + wn;
  int growW  = bm*128 + wm;

  if constexpr (EPI == 2){
    #pragma unroll
    for (int m = 0; m < 4; m++){
      asm volatile("s_waitcnt lgkmcnt(0)" ::: "memory");
      #pragma unroll
      for (int n = 0; n < 4; n++)
        #pragma unroll
        for (int j = 0; j < 4; j++)
          sm.ef[w][lg*4 + j][n*16 + lr] = acc[m][n][j] + bias[cbaseW + n*16 + lr];
      asm volatile("s_waitcnt lgkmcnt(0)" ::: "memory");
      #pragma unroll
      for (int cc = 0; cc < 4; cc++){
        int c = lane + cc*64;
        int row = c >> 4, seg = c & 15;
        int grow = growW + m*16 + row;
        if (grow < M){
          float* gp = (float*)Cp + (size_t)grow*ldc + cbaseW + seg*4;
          f32x4 add = *reinterpret_cast<const f32x4*>(&sm.ef[w][row][seg*4]);
          f32x4 old = *reinterpret_cast<const f32x4*>(gp);
          *reinterpret_cast<f32x4*>(gp) = old + add;
        }
      }
    }
  } else {
    bool vtg_block = (EPI == 0) && (cbaseW >= 1536);
    if (!vtg_block){
      #pragma unroll
      for (int m = 0; m < 4; m++){
        asm volatile("s_waitcnt lgkmcnt(0)" ::: "memory");
        #pragma unroll
        for (int n = 0; n < 4; n++)
          #pragma unroll
          for (int j = 0; j < 4; j++){
            float v = acc[m][n][j] + bias[cbaseW + n*16 + lr];
            if constexpr (EPI == 1) v = 0.5f*v*(1.0f + erff(v*0.70710678118654752f));
            sm.eh[w][lg*4 + j][n*16 + lr] = f2bf(v);
          }
        asm volatile("s_waitcnt lgkmcnt(0)" ::: "memory");
        #pragma unroll
        for (int cc = 0; cc < 2; cc++){
          int c = lane + cc*64;
          int row = c >> 3, seg = c & 7;
          int grow = growW + m*16 + row;
          if (grow < M)
            *reinterpret_cast<short8*>((short*)Cp + (size_t)grow*ldc + cbaseW + seg*8) =
                *reinterpret_cast<const short8*>(&sm.eh[w][row][seg*8]);
        }
      }
    } else {
      #pragma unroll
      for (int m = 0; m < 4; m++){
        #pragma unroll
        for (int n = 0; n < 4; n++){
          int col = cbaseW + n*16 + lr;
          #pragma unroll
          for (int j = 0; j < 4; j++){
            int row = growW + lg*4 + m*16 + j;
            if (row < M){
              float v = acc[m][n][j] + bias[col];
              int bb = row / SP1, kp = row - bb*SP1;
              int c  = col - 1536;
              int hh = c / 96, d = c - hh*96;
              VtG[((size_t)(bb*8 + hh)*96 + d)*VTP + kp] = f2bf(v);
            }
          }
        }
      }
    }
  }
}

// ------- fused attention (flash, ALiBi, KVB=64, K+V reg-prefetch, tail-skip) ----
__global__ __launch_bounds__(256) void attn_kernel(const short* __restrict__ qkv,
                                                   const short* __restrict__ VtG,
                                                   short* __restrict__ o){
  __shared__ __align__(16) short Plds[4][16][72];
  __shared__ __align__(16) short Vt[96][72];
  int wg = xcd_swz(blockIdx.x, 2304);
  int qt = wg % 9; int hh = (wg / 9) & 7; int b = wg / 72;
  int t = threadIdx.x, lane = t & 63, w = t >> 6;
  int lr = lane & 15, lg = lane >> 4;
  int q0 = qt*64 + w*16;
  const int RS = 1536;
  const short* base = qkv + (size_t)b*SP1*RS + hh*HD_;
  const short* kb = base + D_;
  const short* vg = VtG + (size_t)(b*8 + hh)*96*VTP;
  int qrow = q0 + lr; if (qrow > 512) qrow = 512;
  short8 qf[3];
  #pragma unroll
  for (int ks = 0; ks < 3; ks++)
    qf[ks] = *reinterpret_cast<const short8*>(base + (size_t)qrow*RS + ks*32 + lg*8);
  float m[4]    = {-1e30f, -1e30f, -1e30f, -1e30f};
  float lsum[4] = {0.f, 0.f, 0.f, 0.f};
  f32x4 oacc[6] = {};
  float slope = exp2f(-(float)(hh + 1));
  const float scale = 0.10206207261596577f;  // 1/sqrt(96)

  short8 vv[3];
  #pragma unroll
  for (int ii = 0; ii < 3; ii++){
    int i = t + ii*256;
    vv[ii] = *reinterpret_cast<const short8*>(vg + (size_t)(i >> 3)*VTP + (i & 7)*8);
  }
  short8 kff[4][3];
  #pragma unroll
  for (int st = 0; st < 4; st++){
    int tr = st*16 + lr;
    #pragma unroll
    for (int ks = 0; ks < 3; ks++)
      kff[st][ks] = *reinterpret_cast<const short8*>(kb + (size_t)tr*RS + ks*32 + lg*8);
  }

  for (int t0 = 0; t0 < SP1; t0 += 64){
    bool tail = (t0 == 512);
    __syncthreads();
    #pragma unroll
    for (int ii = 0; ii < 3; ii++){
      int i = t + ii*256;
      *reinterpret_cast<short8*>(&Vt[i >> 3][(i & 7)*8]) = vv[ii];
    }
    {
      int tp = t0 + 64; if (tp > 512) tp = 512;
      #pragma unroll
      for (int ii = 0; ii < 3; ii++){
        int i = t + ii*256;
        vv[ii] = *reinterpret_cast<const short8*>(vg + (size_t)(i >> 3)*VTP + tp + (i & 7)*8);
      }
    }
    f32x4 s[4] = {};
    __builtin_amdgcn_s_setprio(1);
    #pragma unroll
    for (int st = 0; st < 4; st++){
      if (st && tail) break;
      #pragma unroll
      for (int ks = 0; ks < 3; ks++)
        s[st] = __builtin_amdgcn_mfma_f32_16x16x32_bf16(qf[ks], kff[st][ks], s[st], 0, 0, 0);
    }
    __builtin_amdgcn_s_setprio(0);
    {
      int tn = t0 + 64; if (tn > 512) tn = 512;
      #pragma unroll
      for (int st = 0; st < 4; st++){
        int tr = tn + st*16 + lr; if (tr > 512) tr = 512;
        #pragma unroll
        for (int ks = 0; ks < 3; ks++)
          kff[st][ks] = *reinterpret_cast<const short8*>(kb + (size_t)tr*RS + ks*32 + lg*8);
      }
    }
    __builtin_amdgcn_sched_barrier(0);
    #pragma unroll
    for (int j = 0; j < 4; j++){
      int qr = q0 + lg*4 + j;
      float v[4]; float mx = -1e30f;
      #pragma unroll
      for (int st = 0; st < 4; st++){
        int tc = t0 + st*16 + lr;
        float sv = (tail && st) ? -1e30f
                 : s[st][j]*scale - slope*fabsf((float)(qr - tc));
        if (tc > 512) sv = -1e30f;
        v[st] = sv; mx = fmaxf(mx, sv);
      }
      mx = fmaxf(mx, __shfl_xor(mx, 1, 64));
      mx = fmaxf(mx, __shfl_xor(mx, 2, 64));
      mx = fmaxf(mx, __shfl_xor(mx, 4, 64));
      mx = fmaxf(mx, __shfl_xor(mx, 8, 64));
      float mn = fmaxf(m[j], mx);
      float corr = __expf(m[j] - mn);
      float rs = 0.f;
      #pragma unroll
      for (int st = 0; st < 4; st++){
        float p = __expf(v[st] - mn); rs += p;
        Plds[w][lg*4 + j][st*16 + lr] = f2bf(p);
      }
      rs += __shfl_xor(rs, 1, 64); rs += __shfl_xor(rs, 2, 64);
      rs += __shfl_xor(rs, 4, 64); rs += __shfl_xor(rs, 8, 64);
      lsum[j] = lsum[j]*corr + rs;
      m[j] = mn;
      #pragma unroll
      for (int n = 0; n < 6; n++) oacc[n][j] *= corr;
    }
    __syncthreads();
    short8 pf0 = *reinterpret_cast<const short8*>(&Plds[w][lr][lg*8]);
    __builtin_amdgcn_s_setprio(1);
    if (!tail){
      short8 pf1 = *reinterpret_cast<const short8*>(&Plds[w][lr][32 + lg*8]);
      #pragma unroll
      for (int n = 0; n < 6; n++){
        short8 vf0 = *reinterpret_cast<const short8*>(&Vt[n*16 + lr][lg*8]);
        short8 vf1 = *reinterpret_cast<const short8*>(&Vt[n*16 + lr][32 + lg*8]);
        oacc[n] = __builtin_amdgcn_mfma_f32_16x16x32_bf16(pf0, vf0, oacc[n], 0, 0, 0);
        oacc[n] = __builtin_amdgcn_mfma_f32_16x16x32_bf16(pf1, vf1, oacc[n], 0, 0, 0);
      }
    } else {
      #pragma unroll
      for (int n = 0; n < 6; n++){
        short8 vf0 = *reinterpret_cast<const short8*>(&Vt[n*16 + lr][lg*8]);
        oacc[n] = __builtin_amdgcn_mfma_f32_16x16x32_bf16(pf0, vf0, oacc[n], 0, 0, 0);
      }
    }
    __builtin_amdgcn_s_setprio(0);
  }
  #pragma unroll
  for (int j = 0; j < 4; j++){
    int qr = q0 + lg*4 + j;
    if (qr <= 512){
      float inv = 1.0f / lsum[j];
      #pragma unroll
      for (int n = 0; n < 6; n++)
        o[((size_t)b*SP1 + qr)*D_ + hh*HD_ + n*16 + lr] = f2bf(oacc[n][j]*inv);
    }
  }
}

// ---------------- head ----------------------------------------------------------
__global__ __launch_bounds__(256) void pool1_kernel(const float* __restrict__ lnfb,
                                                    float* __restrict__ part){
  int bid = blockIdx.x; int b = bid >> 3, c = bid & 7;
  int t = threadIdx.x;
  for (int d = t; d < D_; d += 256){
    const float* pb = lnfb + (size_t)b*SP1*D_ + d;
    float s = 0.f;
    for (int i = 1 + c*64; i <= (c+1)*64; i++) s += pb[(size_t)i*D_];
    part[(size_t)bid*D_ + d] = s;
  }
}

__global__ __launch_bounds__(256) void pool2_kernel(const float* __restrict__ lnfb,
    const float* __restrict__ part, float* __restrict__ pooled_in){
  int b = blockIdx.x, t = threadIdx.x;
  for (int d = t; d < D_; d += 256){
    float s = 0.f;
    #pragma unroll
    for (int c = 0; c < 8; c++) s += part[(size_t)(b*8+c)*D_ + d];
    pooled_in[b*D_ + d] = 0.5f*lnfb[(size_t)b*SP1*D_ + d] + 0.5f*(s*(1.0f/512.0f));
  }
}

__global__ __launch_bounds__(256) void matvec_kernel(const float* __restrict__ in,
    const float* __restrict__ W, const float* __restrict__ bias,
    float* __restrict__ out, int K, int Nn){
  __shared__ float inr[768];
  int nb = Nn >> 8;
  int b = blockIdx.x / nb, jc = blockIdx.x % nb;
  int t = threadIdx.x;
  for (int d = t; d < K; d += 256) inr[d] = in[(size_t)b*K + d];
  __syncthreads();
  int j = jc*256 + t;
  float acc = bias ? bias[j] : 0.0f;
  for (int d = 0; d < K; d++) acc += inr[d]*W[(size_t)d*Nn + j];
  out[(size_t)b*Nn + j] = acc;
}

__global__ __launch_bounds__(256) void norm_kernel(const float* __restrict__ c,
                                                   float* __restrict__ out){
  __shared__ float tmp[4];
  int b = blockIdx.x, t = threadIdx.x;
  float v0 = c[b*512 + t], v1 = c[b*512 + 256 + t];
  float s = block_sum256(v0*v0 + v1*v1, tmp);
  float inv = 1.0f / sqrtf(s);
  out[b*512 + t]       = v0*inv;
  out[b*512 + 256 + t] = v1*inv;
}

// ---------------- host orchestration --------------------------------------------
extern "C" void kernel_launch(void* const* d_in, const int* in_sizes, int n_in,
                              void* d_out, int out_size, void* d_ws, size_t ws_size,
                              hipStream_t stream){
  const int*   sensor_ids = (const int*)d_in[0];
  const int*   state_ids  = (const int*)d_in[1];
  const int*   room_ids   = (const int*)d_in[2];
  const float* coords     = (const float*)d_in[3];
  const float* tdelt      = (const float*)d_in[4];
  const float* emb_sensor = (const float*)d_in[6];
  const float* emb_state  = (const float*)d_in[7];
  const float* emb_room   = (const float*)d_in[8];
  const float* fourier_W  = (const float*)d_in[9];
  const float* fourier_b  = (const float*)d_in[10];
  const float* time_emb   = (const float*)d_in[11];
  const float* cls_tok    = (const float*)d_in[12];
  const float* pos_emb    = (const float*)d_in[13];
  const float* ln1_g = (const float*)d_in[14];
  const float* ln1_b = (const float*)d_in[15];
  const float* Wq = (const float*)d_in[16];
  const float* bq = (const float*)d_in[17];
  const float* Wk = (const float*)d_in[18];
  const float* bk = (const float*)d_in[19];
  const float* Wv = (const float*)d_in[20];
  const float* bv = (const float*)d_in[21];
  const float* Wo = (const float*)d_in[22];
  const float* bo = (const float*)d_in[23];
  const float* ln2_g = (const float*)d_in[24];
  const float* ln2_b = (const float*)d_in[25];
  const float* W1 = (const float*)d_in[26];
  const float* b1 = (const float*)d_in[27];
  const float* W2 = (const float*)d_in[28];
  const float* b2 = (const float*)d_in[29];
  const float* lnf_g = (const float*)d_in[30];
  const float* lnf_b = (const float*)d_in[31];
  const float* pool_W = (const float*)d_in[32];
  const float* pool_b = (const float*)d_in[33];
  const float* clip_W = (const float*)d_in[34];

  const size_t QKV_SH = (size_t)NTOK*1536;
  const size_t VTG_SH = (size_t)256*96*VTP;
  const size_t OB_SH  = (size_t)NTOK*D_;
  size_t big_bytes = (QKV_SH + VTG_SH + OB_SH)*2;

  char* p = (char*)d_ws;
  float* x       = (float*)p; p += (size_t)NTOK*D_*4;
  short* h       = (short*)p; p += (size_t)NTOK*D_*2;
  short* big     = (short*)p; p += big_bytes;
  short* wT      = (short*)p; p += (size_t)7077888*2;
  float* biascat = (float*)p; p += (size_t)6*2304*4;
  float* part      = (float*)p; p += (size_t)256*768*4;
  float* pooled_in = (float*)p; p += (size_t)32*768*4;
  float* pooled    = (float*)p; p += (size_t)32*768*4;
  float* clipv     = (float*)p; p += (size_t)32*512*4;

  short* qkvb  = big;
  short* vtg   = big + QKV_SH;
  short* ob    = vtg + VTG_SH;
  short* wqkvT = wT;                             // [2304][768]
  short* woT   = wqkvT + (size_t)2304*768;       // [768][768]
  short* w1T   = woT   + (size_t)768*768;        // [3072][768]
  short* w2T   = w1T   + (size_t)3072*768;       // [768][3072]
  float* lnfb  = (float*)big;

  embed_kernel<<<NTOK/16, 256, 0, stream>>>(sensor_ids, state_ids, room_ids, coords, tdelt,
      emb_sensor, emb_state, emb_room, fourier_W, fourier_b, time_emb, cls_tok, pos_emb, x);
  concat_bias_kernel<<<54, 256, 0, stream>>>(bq, bk, bv, biascat);

  for (int l = 0; l < 6; l++){
    transpose6_kernel<<<3456, 256, 0, stream>>>(
        Wq + (size_t)l*589824, Wk + (size_t)l*589824, Wv + (size_t)l*589824,
        Wo + (size_t)l*589824, W1 + (size_t)l*2359296, W2 + (size_t)l*2359296,
        wqkvT, woT, w1T, w2T);

    ln_kernel<short><<<NTOK/4, 256, 0, stream>>>(x, ln1_g + l*768, ln1_b + l*768, h);
    gemm_bt<0><<<129*18, 256, 0, stream>>>(h, wqkvT, biascat + l*2304, qkvb, vtg,
                                           NTOK, 768, 1536, 18, 129*18);
    attn_kernel<<<2304, 256, 0, stream>>>(qkvb, vtg, ob);
    gemm_bt<2><<<129*6, 256, 0, stream>>>(ob, woT, bo + l*768, x, nullptr,
                                          NTOK, 768, 768, 6, 129*6);
    ln_kernel<short><<<NTOK/4, 256, 0, stream>>>(x, ln2_g + l*768, ln2_b + l*768, h);
    gemm_bt<1><<<129*24, 256, 0, stream>>>(h, w1T, b1 + l*3072, big, nullptr,
                                           NTOK, 768, 3072, 24, 129*24);
    gemm_bt<2><<<129*6, 256, 0, stream>>>(big, w2T, b2 + l*768, x, nullptr,
                                          NTOK, 3072, 768, 6, 129*6);
  }

  ln_kernel<float><<<NTOK/4, 256, 0, stream>>>(x, lnf_g, lnf_b, lnfb);
  pool1_kernel<<<256, 256, 0, stream>>>(lnfb, part);
  pool2_kernel<<<32, 256, 0, stream>>>(lnfb, part, pooled_in);
  matvec_kernel<<<96, 256, 0, stream>>>(pooled_in, pool_W, pool_b, pooled, 768, 768);
  matvec_kernel<<<64, 256, 0, stream>>>(pooled, clip_W, nullptr, clipv, 768, 512);
  norm_kernel<<<32, 256, 0, stream>>>(clipv, (float*)d_out);
}